// Round 5
// baseline (359.340 us; speedup 1.0000x reference)
//
#include <hip/hip_runtime.h>

// Caser forward, MI355X. B=4096, L=5, D=128, NH=16, NV=4, T=100, FC1=752.
// R2 data: fused 166us latency-bound -> split. R4 data: front 82us
// (VALU 37%, occ 42%, 4 blk/CU, one residency round) -> G=2 + 8 blk/CU
// (32 waves/CU, 2048 blocks). Tail ~78us -> unroll 5 for deeper MLP.

constexpr int Bsz  = 4096;
constexpr int Lq   = 5;
constexpr int Dd   = 128;
constexpr int NHh  = 16;
constexpr int NVv  = 4;
constexpr int Tt   = 100;
constexpr int FC1  = 752;   // 4*128 + 16*15
constexpr int G    = 2;     // batch elems per block (kernel A)
constexpr int NTHR = 256;

// ---------------- Kernel A: emb gather, convs, FC1 -> xc (B x 2D) ----------
__global__ __launch_bounds__(NTHR, 8) void caser_front(
    const int* __restrict__ seq, const int* __restrict__ user,
    const float* __restrict__ item_table, const float* __restrict__ user_table,
    const float* __restrict__ Wv, const float* __restrict__ bv,
    const float* __restrict__ Wh, const float* __restrict__ bh,
    const float* __restrict__ W1, const float* __restrict__ b1,
    float* __restrict__ xc_ws)
{
    __shared__ float emb[G][Lq * Dd];    // 5120 B (reused as `part` in FC1)
    __shared__ float z[G][FC1];          // 6016 B
    __shared__ float xc[G][2 * Dd];      // 2048 B  -> 13184 B total, 8 blk/CU

    const int tid = threadIdx.x;
    const int b0  = blockIdx.x * G;

    // ---- phase 1: emb gather (G*5 rows of 128, coalesced per row) ----
    for (int idx = tid; idx < G * Lq * Dd; idx += NTHR) {
        int gt  = idx >> 7;              // g*L + t
        int d   = idx & (Dd - 1);
        int row = seq[b0 * Lq + gt];
        emb[0][idx] = item_table[row * Dd + d];
    }
    // uemb -> xc[g][128..255]
    for (int idx = tid; idx < G * Dd; idx += NTHR) {
        int g = idx >> 7, d = idx & (Dd - 1);
        xc[g][Dd + d] = user_table[user[b0 + g] * Dd + d];
    }
    __syncthreads();

    // ---- phase 2a: vertical conv -> z[g][0..511] ----
    for (int idx = tid; idx < G * NVv * Dd; idx += NTHR) {
        int g = idx >> 9;
        int v = (idx >> 7) & 3;
        int d = idx & (Dd - 1);
        float acc = bv[v];
        #pragma unroll
        for (int t = 0; t < Lq; ++t)
            acc = fmaf(emb[g][t * Dd + d], Wv[v * Lq + t], acc);
        z[g][v * Dd + d] = acc;
    }

    // ---- phase 2b: horizontal convs -> z[g][512..751] ----
    // thread = (l,t)-group * 16 + f : 15 groups * 16 = 240 threads.
    if (tid < 240) {
        int glt = tid >> 4, f = tid & 15;
        int l, t;
        if      (glt < 5)  { l = 1; t = glt; }
        else if (glt < 9)  { l = 2; t = glt - 5; }
        else if (glt < 12) { l = 3; t = glt - 9; }
        else if (glt < 14) { l = 4; t = glt - 12; }
        else               { l = 5; t = 0; }
        const int lout = Lq - l + 1;
        const int zoff = (l == 1) ? 0 : (l == 2) ? 80 : (l == 3) ? 144
                       : (l == 4) ? 192 : 224;
        float acc[G];
        {
            float bias = bh[(l - 1) * NHh + f];
            #pragma unroll
            for (int g = 0; g < G; ++g) acc[g] = bias;
        }
        for (int s = 0; s < l; ++s) {
            const float4* w4 = reinterpret_cast<const float4*>(
                Wh + (((l - 1) * NHh + f) * Lq + s) * Dd);
            const int ebase = (t + s) * Dd;
            #pragma unroll 4
            for (int d4 = 0; d4 < Dd / 4; ++d4) {
                float4 w = w4[d4];
                #pragma unroll
                for (int g = 0; g < G; ++g) {
                    float4 e = *reinterpret_cast<const float4*>(
                        &emb[g][ebase + d4 * 4]);
                    acc[g] = fmaf(e.x, w.x,
                             fmaf(e.y, w.y,
                             fmaf(e.z, w.z,
                             fmaf(e.w, w.w, acc[g]))));
                }
            }
        }
        #pragma unroll
        for (int g = 0; g < G; ++g)
            z[g][NVv * Dd + zoff + f * lout + t] = fmaxf(acc[g], 0.0f);
    }
    __syncthreads();

    // ---- phase 3: FC1  x = relu(z @ W1 + b1) ----
    float* part = &emb[0][0];            // emb dead; 512 <= 1280 floats
    {
        int j = tid & (Dd - 1);
        int half = tid >> 7;
        float acc[G];
        #pragma unroll
        for (int g = 0; g < G; ++g) acc[g] = 0.f;
        const float* w1p = W1 + j;
        int i0 = half * (FC1 / 2);
        for (int i = i0; i < i0 + FC1 / 2; i += 4) {
            float4 zz[G];
            #pragma unroll
            for (int g = 0; g < G; ++g)
                zz[g] = *reinterpret_cast<const float4*>(&z[g][i]);
            float w0 = w1p[(i + 0) * Dd];
            float w1 = w1p[(i + 1) * Dd];
            float w2 = w1p[(i + 2) * Dd];
            float w3 = w1p[(i + 3) * Dd];
            #pragma unroll
            for (int g = 0; g < G; ++g)
                acc[g] = fmaf(zz[g].x, w0,
                         fmaf(zz[g].y, w1,
                         fmaf(zz[g].z, w2,
                         fmaf(zz[g].w, w3, acc[g]))));
        }
        #pragma unroll
        for (int g = 0; g < G; ++g)
            part[(half * G + g) * Dd + j] = acc[g];
    }
    __syncthreads();
    if (tid < Dd) {
        #pragma unroll
        for (int g = 0; g < G; ++g)
            xc[g][tid] = fmaxf(part[g * Dd + tid] + part[(G + g) * Dd + tid]
                               + b1[tid], 0.0f);
    }
    __syncthreads();

    // ---- write xc to workspace, coalesced ----
    for (int idx = tid; idx < G * 2 * Dd; idx += NTHR)
        xc_ws[b0 * 2 * Dd + idx] = xc[0][idx];
}

// ---------------- Kernel B: res[b][t] = dot(W2_table[item], xc[b]) + b2 ----
// One block per b; 4 waves, each owns t = wv + 4k (25 serial items).
// 32 waves/CU; unroll 5 keeps ~5 KB of row-loads in flight per wave.
__global__ __launch_bounds__(NTHR, 8) void caser_tail(
    const int* __restrict__ items,
    const float* __restrict__ W2_table, const float* __restrict__ b2_table,
    const float* __restrict__ xc_ws, float* __restrict__ out)
{
    __shared__ int   s_items[Tt];
    __shared__ float s_b2[Tt];

    const int b    = blockIdx.x;
    const int tid  = threadIdx.x;
    const int lane = tid & 63;
    const int wv   = tid >> 6;

    if (tid < Tt) {
        int it = items[b * Tt + tid];
        s_items[tid] = it;
        s_b2[tid]    = b2_table[it];
    }
    const float4 xf =
        reinterpret_cast<const float4*>(xc_ws + b * 2 * Dd)[lane];
    __syncthreads();

    #pragma unroll 5
    for (int k = 0; k < Tt / 4; ++k) {
        const int t = wv + k * 4;
        const float4* wp = reinterpret_cast<const float4*>(
            W2_table + (size_t)s_items[t] * (2 * Dd));
        float4 w = wp[lane];
        float v = fmaf(w.x, xf.x,
                  fmaf(w.y, xf.y,
                  fmaf(w.z, xf.z, w.w * xf.w)));
        #pragma unroll
        for (int off = 32; off; off >>= 1)
            v += __shfl_xor(v, off);
        if (lane == 0) out[b * Tt + t] = v + s_b2[t];
    }
}

extern "C" void kernel_launch(void* const* d_in, const int* in_sizes, int n_in,
                              void* d_out, int out_size, void* d_ws, size_t ws_size,
                              hipStream_t stream) {
    const int*   seq        = (const int*)  d_in[0];
    const int*   user       = (const int*)  d_in[1];
    const int*   items      = (const int*)  d_in[2];
    const float* item_table = (const float*)d_in[3];
    const float* user_table = (const float*)d_in[4];
    const float* Wv         = (const float*)d_in[5];
    const float* bv         = (const float*)d_in[6];
    const float* Wh         = (const float*)d_in[7];
    const float* bh         = (const float*)d_in[8];
    const float* W1         = (const float*)d_in[9];
    const float* b1         = (const float*)d_in[10];
    const float* W2_table   = (const float*)d_in[11];
    const float* b2_table   = (const float*)d_in[12];
    float* out   = (float*)d_out;
    float* xc_ws = (float*)d_ws;         // B * 2D floats = 4 MB

    caser_front<<<dim3(Bsz / G), dim3(NTHR), 0, stream>>>(
        seq, user, item_table, user_table, Wv, bv, Wh, bh, W1, b1, xc_ws);
    caser_tail<<<dim3(Bsz), dim3(NTHR), 0, stream>>>(
        items, W2_table, b2_table, xc_ws, out);
}

// Round 6
// 330.659 us; speedup vs baseline: 1.0867x; 1.0867x over previous
//
#include <hip/hip_runtime.h>

// Caser forward, MI355X. B=4096, L=5, D=128, NH=16, NV=4, T=100, FC1=752.
// R4: front(G=4,lb4) 82us, VALU 37%, occ 42% -> latency-bound on FC1 W1 loads.
// R5: G=2+lb8 -> VGPR 32 -> ILP collapse -> 115us. REVERT to G=4; fix ILP:
//   lb(256,6) (VGPR cap 85) + FC1 unroll 8 (8 W1 rows in flight).
// Tail: lb(256,6) so unroll-5 row pipeline fits in registers (was 32 VGPR).

constexpr int Bsz  = 4096;
constexpr int Lq   = 5;
constexpr int Dd   = 128;
constexpr int NHh  = 16;
constexpr int NVv  = 4;
constexpr int Tt   = 100;
constexpr int FC1  = 752;   // 4*128 + 16*15
constexpr int G    = 4;     // batch elems per block (kernel A)
constexpr int NTHR = 256;

// ---------------- Kernel A: emb gather, convs, FC1 -> xc (B x 2D) ----------
__global__ __launch_bounds__(NTHR, 6) void caser_front(
    const int* __restrict__ seq, const int* __restrict__ user,
    const float* __restrict__ item_table, const float* __restrict__ user_table,
    const float* __restrict__ Wv, const float* __restrict__ bv,
    const float* __restrict__ Wh, const float* __restrict__ bh,
    const float* __restrict__ W1, const float* __restrict__ b1,
    float* __restrict__ xc_ws)
{
    __shared__ float emb[G][Lq * Dd];    // 10240 B (reused as `part` in FC1)
    __shared__ float z[G][FC1];          // 12032 B
    __shared__ float xc[G][2 * Dd];      // 4096 B -> 26368 B, 6 blk/CU max

    const int tid = threadIdx.x;
    const int b0  = blockIdx.x * G;

    // ---- phase 1: emb gather (G*5 rows of 128, coalesced per row) ----
    for (int idx = tid; idx < G * Lq * Dd; idx += NTHR) {
        int gt  = idx >> 7;              // g*L + t
        int d   = idx & (Dd - 1);
        int row = seq[b0 * Lq + gt];
        emb[0][idx] = item_table[row * Dd + d];
    }
    // uemb -> xc[g][128..255]
    for (int idx = tid; idx < G * Dd; idx += NTHR) {
        int g = idx >> 7, d = idx & (Dd - 1);
        xc[g][Dd + d] = user_table[user[b0 + g] * Dd + d];
    }
    __syncthreads();

    // ---- phase 2a: vertical conv -> z[g][0..511] ----
    for (int idx = tid; idx < G * NVv * Dd; idx += NTHR) {
        int g = idx >> 9;
        int v = (idx >> 7) & 3;
        int d = idx & (Dd - 1);
        float acc = bv[v];
        #pragma unroll
        for (int t = 0; t < Lq; ++t)
            acc = fmaf(emb[g][t * Dd + d], Wv[v * Lq + t], acc);
        z[g][v * Dd + d] = acc;
    }

    // ---- phase 2b: horizontal convs -> z[g][512..751] ----
    // thread = (l,t)-group * 16 + f : 15 groups * 16 = 240 threads.
    if (tid < 240) {
        int glt = tid >> 4, f = tid & 15;
        int l, t;
        if      (glt < 5)  { l = 1; t = glt; }
        else if (glt < 9)  { l = 2; t = glt - 5; }
        else if (glt < 12) { l = 3; t = glt - 9; }
        else if (glt < 14) { l = 4; t = glt - 12; }
        else               { l = 5; t = 0; }
        const int lout = Lq - l + 1;
        const int zoff = (l == 1) ? 0 : (l == 2) ? 80 : (l == 3) ? 144
                       : (l == 4) ? 192 : 224;
        float acc[G];
        {
            float bias = bh[(l - 1) * NHh + f];
            #pragma unroll
            for (int g = 0; g < G; ++g) acc[g] = bias;
        }
        for (int s = 0; s < l; ++s) {
            const float4* w4 = reinterpret_cast<const float4*>(
                Wh + (((l - 1) * NHh + f) * Lq + s) * Dd);
            const int ebase = (t + s) * Dd;
            #pragma unroll 4
            for (int d4 = 0; d4 < Dd / 4; ++d4) {
                float4 w = w4[d4];
                #pragma unroll
                for (int g = 0; g < G; ++g) {
                    float4 e = *reinterpret_cast<const float4*>(
                        &emb[g][ebase + d4 * 4]);
                    acc[g] = fmaf(e.x, w.x,
                             fmaf(e.y, w.y,
                             fmaf(e.z, w.z,
                             fmaf(e.w, w.w, acc[g]))));
                }
            }
        }
        #pragma unroll
        for (int g = 0; g < G; ++g)
            z[g][NVv * Dd + zoff + f * lout + t] = fmaxf(acc[g], 0.0f);
    }
    __syncthreads();

    // ---- phase 3: FC1  x = relu(z @ W1 + b1), unroll 8 (376 = 8*47) ----
    float* part = &emb[0][0];            // emb dead; 1024 <= 2560 floats
    {
        int j = tid & (Dd - 1);
        int half = tid >> 7;
        float acc[G];
        #pragma unroll
        for (int g = 0; g < G; ++g) acc[g] = 0.f;
        const float* w1p = W1 + j;
        int i0 = half * (FC1 / 2);
        for (int i = i0; i < i0 + FC1 / 2; i += 8) {
            // issue all 8 W1 row loads + all z reads up front
            float w0 = w1p[(i + 0) * Dd];
            float w1 = w1p[(i + 1) * Dd];
            float w2 = w1p[(i + 2) * Dd];
            float w3 = w1p[(i + 3) * Dd];
            float w4 = w1p[(i + 4) * Dd];
            float w5 = w1p[(i + 5) * Dd];
            float w6 = w1p[(i + 6) * Dd];
            float w7 = w1p[(i + 7) * Dd];
            float4 za[G], zb[G];
            #pragma unroll
            for (int g = 0; g < G; ++g) {
                za[g] = *reinterpret_cast<const float4*>(&z[g][i]);
                zb[g] = *reinterpret_cast<const float4*>(&z[g][i + 4]);
            }
            #pragma unroll
            for (int g = 0; g < G; ++g) {
                acc[g] = fmaf(za[g].x, w0,
                         fmaf(za[g].y, w1,
                         fmaf(za[g].z, w2,
                         fmaf(za[g].w, w3, acc[g]))));
                acc[g] = fmaf(zb[g].x, w4,
                         fmaf(zb[g].y, w5,
                         fmaf(zb[g].z, w6,
                         fmaf(zb[g].w, w7, acc[g]))));
            }
        }
        #pragma unroll
        for (int g = 0; g < G; ++g)
            part[(half * G + g) * Dd + j] = acc[g];
    }
    __syncthreads();
    if (tid < Dd) {
        #pragma unroll
        for (int g = 0; g < G; ++g)
            xc[g][tid] = fmaxf(part[g * Dd + tid] + part[(G + g) * Dd + tid]
                               + b1[tid], 0.0f);
    }
    __syncthreads();

    // ---- write xc to workspace, coalesced ----
    for (int idx = tid; idx < G * 2 * Dd; idx += NTHR)
        xc_ws[b0 * 2 * Dd + idx] = xc[0][idx];
}

// ---------------- Kernel B: res[b][t] = dot(W2_table[item], xc[b]) + b2 ----
// One block per b; 4 waves, each owns t = wv + 4k (25 serial items).
// lb(256,6): VGPR cap 85 so the unroll-5 pipeline (5 rows in flight,
// ~55 regs) actually fits; 6 blk/CU = 24 waves/CU.
__global__ __launch_bounds__(NTHR, 6) void caser_tail(
    const int* __restrict__ items,
    const float* __restrict__ W2_table, const float* __restrict__ b2_table,
    const float* __restrict__ xc_ws, float* __restrict__ out)
{
    __shared__ int   s_items[Tt];
    __shared__ float s_b2[Tt];

    const int b    = blockIdx.x;
    const int tid  = threadIdx.x;
    const int lane = tid & 63;
    const int wv   = tid >> 6;

    if (tid < Tt) {
        int it = items[b * Tt + tid];
        s_items[tid] = it;
        s_b2[tid]    = b2_table[it];
    }
    const float4 xf =
        reinterpret_cast<const float4*>(xc_ws + b * 2 * Dd)[lane];
    __syncthreads();

    #pragma unroll 5
    for (int k = 0; k < Tt / 4; ++k) {
        const int t = wv + k * 4;
        const float4* wp = reinterpret_cast<const float4*>(
            W2_table + (size_t)s_items[t] * (2 * Dd));
        float4 w = wp[lane];
        float v = fmaf(w.x, xf.x,
                  fmaf(w.y, xf.y,
                  fmaf(w.z, xf.z, w.w * xf.w)));
        #pragma unroll
        for (int off = 32; off; off >>= 1)
            v += __shfl_xor(v, off);
        if (lane == 0) out[b * Tt + t] = v + s_b2[t];
    }
}

extern "C" void kernel_launch(void* const* d_in, const int* in_sizes, int n_in,
                              void* d_out, int out_size, void* d_ws, size_t ws_size,
                              hipStream_t stream) {
    const int*   seq        = (const int*)  d_in[0];
    const int*   user       = (const int*)  d_in[1];
    const int*   items      = (const int*)  d_in[2];
    const float* item_table = (const float*)d_in[3];
    const float* user_table = (const float*)d_in[4];
    const float* Wv         = (const float*)d_in[5];
    const float* bv         = (const float*)d_in[6];
    const float* Wh         = (const float*)d_in[7];
    const float* bh         = (const float*)d_in[8];
    const float* W1         = (const float*)d_in[9];
    const float* b1         = (const float*)d_in[10];
    const float* W2_table   = (const float*)d_in[11];
    const float* b2_table   = (const float*)d_in[12];
    float* out   = (float*)d_out;
    float* xc_ws = (float*)d_ws;         // B * 2D floats = 4 MB

    caser_front<<<dim3(Bsz / G), dim3(NTHR), 0, stream>>>(
        seq, user, item_table, user_table, Wv, bv, Wh, bh, W1, b1, xc_ws);
    caser_tail<<<dim3(Bsz), dim3(NTHR), 0, stream>>>(
        items, W2_table, b2_table, xc_ws, out);
}

// Round 7
// 327.122 us; speedup vs baseline: 1.0985x; 1.0108x over previous
//
#include <hip/hip_runtime.h>

// Caser forward, MI355X. B=4096, L=5, D=128, NH=16, NV=4, T=100, FC1=752.
// R6 data: front 85us, VALU 33%, occ 42% (grid-capped), LDS_BANK_CONFLICT
// 3.7M (4-way on P2b emb reads: t-groups 512B apart = same banks).
// R7: pad emb stride 132 (bank shift 4/t); FC1 = float2-j x K-quarter split
// (chain 376->188) + depth-2 manual prefetch; lb(256,4). Tail unchanged.

constexpr int Bsz  = 4096;
constexpr int Lq   = 5;
constexpr int Dd   = 128;
constexpr int EP   = 132;   // padded emb row stride (floats): bank shift 4
constexpr int NHh  = 16;
constexpr int NVv  = 4;
constexpr int Tt   = 100;
constexpr int FC1  = 752;   // 4*128 + 16*15
constexpr int KQ   = FC1 / 4;  // 188 per K-quarter
constexpr int G    = 4;     // batch elems per block (kernel A)
constexpr int NTHR = 256;

// ---------------- Kernel A: emb gather, convs, FC1 -> xc (B x 2D) ----------
__global__ __launch_bounds__(NTHR, 4) void caser_front(
    const int* __restrict__ seq, const int* __restrict__ user,
    const float* __restrict__ item_table, const float* __restrict__ user_table,
    const float* __restrict__ Wv, const float* __restrict__ bv,
    const float* __restrict__ Wh, const float* __restrict__ bh,
    const float* __restrict__ W1, const float* __restrict__ b1,
    float* __restrict__ xc_ws)
{
    __shared__ float emb[G][Lq * EP];    // 10560 B, padded; reused as `part`
    __shared__ float z[G][FC1];          // 12032 B
    __shared__ float xc[G][2 * Dd];      // 4096 B -> 26688 B total

    const int tid = threadIdx.x;
    const int b0  = blockIdx.x * G;
    float* embf = &emb[0][0];            // row gt at embf[gt*EP], g at g*5*EP

    // ---- phase 1: emb gather (G*5 rows of 128, coalesced per row) ----
    for (int idx = tid; idx < G * Lq * Dd; idx += NTHR) {
        int gt  = idx >> 7;              // g*L + t
        int d   = idx & (Dd - 1);
        int row = seq[b0 * Lq + gt];
        embf[gt * EP + d] = item_table[row * Dd + d];
    }
    // uemb -> xc[g][128..255]
    for (int idx = tid; idx < G * Dd; idx += NTHR) {
        int g = idx >> 7, d = idx & (Dd - 1);
        xc[g][Dd + d] = user_table[user[b0 + g] * Dd + d];
    }
    __syncthreads();

    // ---- phase 2a: vertical conv -> z[g][0..511] ----
    for (int idx = tid; idx < G * NVv * Dd; idx += NTHR) {
        int g = idx >> 9;
        int v = (idx >> 7) & 3;
        int d = idx & (Dd - 1);
        float acc = bv[v];
        #pragma unroll
        for (int t = 0; t < Lq; ++t)
            acc = fmaf(emb[g][t * EP + d], Wv[v * Lq + t], acc);
        z[g][v * Dd + d] = acc;
    }

    // ---- phase 2b: horizontal convs -> z[g][512..751] ----
    // thread = (l,t)-group * 16 + f : 15 groups * 16 = 240 threads.
    // emb reads: 16-lane broadcast per group; padded stride -> 4 groups on
    // disjoint banks. Depth-2 prefetch on the Wh float4 stream.
    if (tid < 240) {
        int glt = tid >> 4, f = tid & 15;
        int l, t;
        if      (glt < 5)  { l = 1; t = glt; }
        else if (glt < 9)  { l = 2; t = glt - 5; }
        else if (glt < 12) { l = 3; t = glt - 9; }
        else if (glt < 14) { l = 4; t = glt - 12; }
        else               { l = 5; t = 0; }
        const int lout = Lq - l + 1;
        const int zoff = (l == 1) ? 0 : (l == 2) ? 80 : (l == 3) ? 144
                       : (l == 4) ? 192 : 224;
        float acc[G];
        {
            float bias = bh[(l - 1) * NHh + f];
            #pragma unroll
            for (int g = 0; g < G; ++g) acc[g] = bias;
        }
        const float4* w4 = reinterpret_cast<const float4*>(
            Wh + (((l - 1) * NHh + f) * Lq) * Dd);   // row s at w4[s*32+d4]
        float4 wc = w4[t == t ? 0 : 0];              // first element
        wc = w4[0];
        const int niter = l * 32;                    // flat (s,d4) stream
        for (int it = 0; it < niter; ++it) {
            float4 wn = (it + 1 < niter) ? w4[it + 1] : wc;
            const int s  = it >> 5;
            const int d4 = it & 31;
            const int ebase = (t + s) * EP + d4 * 4;
            #pragma unroll
            for (int g = 0; g < G; ++g) {
                float4 e = *reinterpret_cast<const float4*>(
                    &embf[g * Lq * EP + ebase]);
                acc[g] = fmaf(e.x, wc.x,
                         fmaf(e.y, wc.y,
                         fmaf(e.z, wc.z,
                         fmaf(e.w, wc.w, acc[g]))));
            }
            wc = wn;
        }
        #pragma unroll
        for (int g = 0; g < G; ++g)
            z[g][NVv * Dd + zoff + f * lout + t] = fmaxf(acc[g], 0.0f);
    }
    __syncthreads();

    // ---- phase 3: FC1  x = relu(z @ W1 + b1) ----
    // thread = (q = K-quarter, j2): covers cols {2*j2, 2*j2+1}, rows
    // i in [q*188, q*188+188). float2 W1 loads (512B/wave, coalesced);
    // z reads wave-uniform (broadcast). Depth-2 chunk prefetch, chunk=4.
    float* part = &embf[0];              // emb dead; 2048 <= 2640 floats
    {
        const int q  = tid >> 6;
        const int j2 = tid & 63;
        const float* w1p = W1 + 2 * j2;  // + i*Dd per row
        float2 acc[G];
        #pragma unroll
        for (int g = 0; g < G; ++g) acc[g] = make_float2(0.f, 0.f);
        const int i0 = q * KQ;
        float2 cw0, cw1, cw2, cw3, nw0, nw1, nw2, nw3;
        cw0 = *reinterpret_cast<const float2*>(w1p + (i0 + 0) * Dd);
        cw1 = *reinterpret_cast<const float2*>(w1p + (i0 + 1) * Dd);
        cw2 = *reinterpret_cast<const float2*>(w1p + (i0 + 2) * Dd);
        cw3 = *reinterpret_cast<const float2*>(w1p + (i0 + 3) * Dd);
        for (int i = i0; i < i0 + KQ - 4; i += 4) {
            nw0 = *reinterpret_cast<const float2*>(w1p + (i + 4) * Dd);
            nw1 = *reinterpret_cast<const float2*>(w1p + (i + 5) * Dd);
            nw2 = *reinterpret_cast<const float2*>(w1p + (i + 6) * Dd);
            nw3 = *reinterpret_cast<const float2*>(w1p + (i + 7) * Dd);
            #pragma unroll
            for (int g = 0; g < G; ++g) {
                float4 zz = *reinterpret_cast<const float4*>(&z[g][i]);
                acc[g].x = fmaf(zz.w, cw3.x, fmaf(zz.z, cw2.x,
                           fmaf(zz.y, cw1.x, fmaf(zz.x, cw0.x, acc[g].x))));
                acc[g].y = fmaf(zz.w, cw3.y, fmaf(zz.z, cw2.y,
                           fmaf(zz.y, cw1.y, fmaf(zz.x, cw0.y, acc[g].y))));
            }
            cw0 = nw0; cw1 = nw1; cw2 = nw2; cw3 = nw3;
        }
        {   // epilogue chunk (i = i0 + KQ - 4)
            const int i = i0 + KQ - 4;
            #pragma unroll
            for (int g = 0; g < G; ++g) {
                float4 zz = *reinterpret_cast<const float4*>(&z[g][i]);
                acc[g].x = fmaf(zz.w, cw3.x, fmaf(zz.z, cw2.x,
                           fmaf(zz.y, cw1.x, fmaf(zz.x, cw0.x, acc[g].x))));
                acc[g].y = fmaf(zz.w, cw3.y, fmaf(zz.z, cw2.y,
                           fmaf(zz.y, cw1.y, fmaf(zz.x, cw0.y, acc[g].y))));
            }
        }
        #pragma unroll
        for (int g = 0; g < G; ++g)
            *reinterpret_cast<float2*>(&part[(q * G + g) * Dd + 2 * j2])
                = acc[g];
    }
    __syncthreads();
    if (tid < Dd) {
        #pragma unroll
        for (int g = 0; g < G; ++g) {
            float s = part[g * Dd + tid]
                    + part[(G + g) * Dd + tid]
                    + part[(2 * G + g) * Dd + tid]
                    + part[(3 * G + g) * Dd + tid];
            xc[g][tid] = fmaxf(s + b1[tid], 0.0f);
        }
    }
    __syncthreads();

    // ---- write xc to workspace, coalesced ----
    for (int idx = tid; idx < G * 2 * Dd; idx += NTHR)
        xc_ws[b0 * 2 * Dd + idx] = xc[0][idx];
}

// ---------------- Kernel B: res[b][t] = dot(W2_table[item], xc[b]) + b2 ----
// One block per b; 4 waves, each owns t = wv + 4k (25 serial items).
// UNCHANGED from R6 for clean A/B on the front.
__global__ __launch_bounds__(NTHR, 6) void caser_tail(
    const int* __restrict__ items,
    const float* __restrict__ W2_table, const float* __restrict__ b2_table,
    const float* __restrict__ xc_ws, float* __restrict__ out)
{
    __shared__ int   s_items[Tt];
    __shared__ float s_b2[Tt];

    const int b    = blockIdx.x;
    const int tid  = threadIdx.x;
    const int lane = tid & 63;
    const int wv   = tid >> 6;

    if (tid < Tt) {
        int it = items[b * Tt + tid];
        s_items[tid] = it;
        s_b2[tid]    = b2_table[it];
    }
    const float4 xf =
        reinterpret_cast<const float4*>(xc_ws + b * 2 * Dd)[lane];
    __syncthreads();

    #pragma unroll 5
    for (int k = 0; k < Tt / 4; ++k) {
        const int t = wv + k * 4;
        const float4* wp = reinterpret_cast<const float4*>(
            W2_table + (size_t)s_items[t] * (2 * Dd));
        float4 w = wp[lane];
        float v = fmaf(w.x, xf.x,
                  fmaf(w.y, xf.y,
                  fmaf(w.z, xf.z, w.w * xf.w)));
        #pragma unroll
        for (int off = 32; off; off >>= 1)
            v += __shfl_xor(v, off);
        if (lane == 0) out[b * Tt + t] = v + s_b2[t];
    }
}

extern "C" void kernel_launch(void* const* d_in, const int* in_sizes, int n_in,
                              void* d_out, int out_size, void* d_ws, size_t ws_size,
                              hipStream_t stream) {
    const int*   seq        = (const int*)  d_in[0];
    const int*   user       = (const int*)  d_in[1];
    const int*   items      = (const int*)  d_in[2];
    const float* item_table = (const float*)d_in[3];
    const float* user_table = (const float*)d_in[4];
    const float* Wv         = (const float*)d_in[5];
    const float* bv         = (const float*)d_in[6];
    const float* Wh         = (const float*)d_in[7];
    const float* bh         = (const float*)d_in[8];
    const float* W1         = (const float*)d_in[9];
    const float* b1         = (const float*)d_in[10];
    const float* W2_table   = (const float*)d_in[11];
    const float* b2_table   = (const float*)d_in[12];
    float* out   = (float*)d_out;
    float* xc_ws = (float*)d_ws;         // B * 2D floats = 4 MB

    caser_front<<<dim3(Bsz / G), dim3(NTHR), 0, stream>>>(
        seq, user, item_table, user_table, Wv, bv, Wh, bh, W1, b1, xc_ws);
    caser_tail<<<dim3(Bsz), dim3(NTHR), 0, stream>>>(
        items, W2_table, b2_table, xc_ws, out);
}